// Round 1
// baseline (549.047 us; speedup 1.0000x reference)
//
#include <hip/hip_runtime.h>
#include <hip/hip_bf16.h>

#define B_  2
#define T_  2048
#define C_  1024
#define H_  8
#define HD_ 128
#define M_  (B_*T_)   // 4096

typedef short  bf16x8 __attribute__((ext_vector_type(8)));
typedef float  f32x4  __attribute__((ext_vector_type(4)));

typedef const __attribute__((address_space(1))) void* gas_ptr;
typedef __attribute__((address_space(3))) void*       las_ptr;

static __device__ __forceinline__ unsigned short f2bf(float f) {
    unsigned int u = __float_as_uint(f);
    u += 0x7fffu + ((u >> 16) & 1u);   // round-to-nearest-even
    return (unsigned short)(u >> 16);
}

static __device__ __forceinline__ float readlane_f(float v, int l) {
    return __uint_as_float(__builtin_amdgcn_readlane(__float_as_uint(v), l));
}

// ---------------- fp32 -> bf16 conversion (vectorized) ----------------
__global__ __launch_bounds__(256) void k_f32_to_bf16(const float* __restrict__ in,
                                                     unsigned short* __restrict__ out,
                                                     int n4) {
    int i = blockIdx.x * 256 + threadIdx.x;
    if (i >= n4) return;
    float4 v = reinterpret_cast<const float4*>(in)[i];
    ushort4 o;
    o.x = f2bf(v.x); o.y = f2bf(v.y); o.z = f2bf(v.z); o.w = f2bf(v.w);
    reinterpret_cast<ushort4*>(out)[i] = o;
}

// ---------------- q/k tiny projection: q~[B,H,T,4], k~[B,H,T,4] ----------------
__global__ __launch_bounds__(256) void k_proj_qk(const float* __restrict__ x,
                                                 const float* __restrict__ Wq,
                                                 const float* __restrict__ Wk,
                                                 const float* __restrict__ scale_p,
                                                 float* __restrict__ qt,
                                                 float* __restrict__ kt) {
    __shared__ __align__(16) float xrow[C_];
    __shared__ float qk3[48];
    const int row = blockIdx.x;          // b*T + t
    const int tid = threadIdx.x;

    reinterpret_cast<float4*>(xrow)[tid] =
        reinterpret_cast<const float4*>(x + (size_t)row * C_)[tid];
    __syncthreads();

    if (tid < 192) {
        int o = tid >> 2, part = tid & 3;
        const float* wrow = (o < 24) ? (Wq + (size_t)o * C_) : (Wk + (size_t)(o - 24) * C_);
        int k0 = part * 256;
        float s = 0.f;
        #pragma unroll 8
        for (int k = 0; k < 256; k += 4) {
            float4 wv = *reinterpret_cast<const float4*>(wrow + k0 + k);
            float4 xv = *reinterpret_cast<const float4*>(xrow + k0 + k);
            s += wv.x * xv.x + wv.y * xv.y + wv.z * xv.z + wv.w * xv.w;
        }
        s += __shfl_xor(s, 1);
        s += __shfl_xor(s, 2);
        if (part == 0) qk3[o] = s;
    }
    __syncthreads();

    if (tid < 16) {
        int isK = tid >> 3, h = tid & 7;
        const float r3 = 0.57735026918962576f;   // 1/sqrt(3)
        float d0 = (h & 4) ? r3 : -r3;
        float d1 = (h & 2) ? r3 : -r3;
        float d2 = (h & 1) ? r3 : -r3;
        const float* v3 = qk3 + isK * 24 + h * 3;
        float a = v3[0], b = v3[1], c = v3[2];
        float ond = a * d0 + b * d1 + c * d2;
        float sc = scale_p[0];
        float4 ov = isK ? make_float4(a, b, c, ond)
                        : make_float4(a * sc, b * sc, c * sc, ond);
        float* dst = isK ? kt : qt;
        int b_ = row >> 11, t_idx = row & (T_ - 1);
        reinterpret_cast<float4*>(dst)[(size_t)(b_ * H_ + h) * T_ + t_idx] = ov;
    }
}

// ---------------- bf16 MFMA GEMM: C[M,N] = A[M,K] * B[N,K]^T ----------------
// 128x128 tile, BK=32, 4 waves (2x2), each wave 64x64 (4x4 frags of 16x16x32)
__global__ __launch_bounds__(256) void k_gemm_bf16(const unsigned short* __restrict__ A,
                                                   const unsigned short* __restrict__ Bw,
                                                   float* __restrict__ Cout,
                                                   int Mdim, int Ndim, int Kdim) {
    __shared__ __align__(16) unsigned short lds_a[4][128][8];  // [kq][row][8]
    __shared__ __align__(16) unsigned short lds_b[4][128][8];
    const int tid = threadIdx.x;
    const int nbn = Ndim >> 7;
    const int bm = (blockIdx.x / nbn) << 7;
    const int bn = (blockIdx.x % nbn) << 7;
    const int w = tid >> 6, l = tid & 63;
    const int wm = ((w >> 1) << 6), wn = ((w & 1) << 6);
    const int lh = l & 15, lq = l >> 4;

    f32x4 acc[4][4];
    #pragma unroll
    for (int i = 0; i < 4; ++i)
        #pragma unroll
        for (int j = 0; j < 4; ++j)
            acc[i][j] = (f32x4){0.f, 0.f, 0.f, 0.f};

    for (int k0 = 0; k0 < Kdim; k0 += 32) {
        #pragma unroll
        for (int p = 0; p < 2; ++p) {
            int flat = p * 256 + tid;
            int kq = flat >> 7, row = flat & 127;
            const unsigned short* ga = A + (size_t)(bm + row) * Kdim + k0 + kq * 8;
            __builtin_amdgcn_global_load_lds((gas_ptr)(const void*)ga,
                (las_ptr)(void*)(&lds_a[0][0][0] + (size_t)flat * 8), 16, 0, 0);
            const unsigned short* gb = Bw + (size_t)(bn + row) * Kdim + k0 + kq * 8;
            __builtin_amdgcn_global_load_lds((gas_ptr)(const void*)gb,
                (las_ptr)(void*)(&lds_b[0][0][0] + (size_t)flat * 8), 16, 0, 0);
        }
        __syncthreads();

        bf16x8 af[4], bfr[4];
        #pragma unroll
        for (int f = 0; f < 4; ++f)
            af[f] = *reinterpret_cast<const bf16x8*>(&lds_a[lq][wm + f * 16 + lh][0]);
        #pragma unroll
        for (int f = 0; f < 4; ++f)
            bfr[f] = *reinterpret_cast<const bf16x8*>(&lds_b[lq][wn + f * 16 + lh][0]);
        #pragma unroll
        for (int i = 0; i < 4; ++i)
            #pragma unroll
            for (int j = 0; j < 4; ++j)
                acc[i][j] = __builtin_amdgcn_mfma_f32_16x16x32_bf16(af[i], bfr[j], acc[i][j], 0, 0, 0);
        __syncthreads();
    }

    #pragma unroll
    for (int i = 0; i < 4; ++i) {
        int rbase = bm + wm + i * 16 + lq * 4;
        #pragma unroll
        for (int j = 0; j < 4; ++j) {
            int cidx = bn + wn + j * 16 + lh;
            #pragma unroll
            for (int r = 0; r < 4; ++r)
                Cout[(size_t)(rbase + r) * Ndim + cidx] = acc[i][j][r];
        }
    }
}

// ---------------- flash attention (VALU fp32), rank-4 scores ----------------
// grid: 64 qtiles (heavy first) x 16 (b,h); block: 4 waves x 8 q-rows = 32 rows
__global__ __launch_bounds__(256) void k_attn(const float* __restrict__ qt,
                                              const float* __restrict__ kt,
                                              const float* __restrict__ v,
                                              unsigned short* __restrict__ out) {
    const int tid  = threadIdx.x;
    const int w    = tid >> 6, lane = tid & 63;
    const int bid  = blockIdx.x;
    const int bh   = bid & 15;
    const int qi   = 63 - (bid >> 4);        // heavy tiles get low blockIdx
    const int b    = bh >> 3, h = bh & 7;
    const int q0   = qi << 5;
    const int nt   = qi + 1;
    const int l5   = lane & 31;

    float2 acc[8];
    float  m[8], lsum[8];
    #pragma unroll
    for (int r = 0; r < 8; ++r) { acc[r] = make_float2(0.f, 0.f); m[r] = -1e30f; lsum[r] = 0.f; }

    const float*  vbase = v + (size_t)b * T_ * C_ + h * HD_ + 2 * lane;
    const float4* ktb   = reinterpret_cast<const float4*>(kt) + (size_t)bh * T_;
    const float4* qtb   = reinterpret_cast<const float4*>(qt) + (size_t)bh * T_;
    const int     trow  = q0 + w * 8;

    for (int st = 0; st < nt; ++st) {
        const int s0 = st << 5;
        float4 k4 = ktb[s0 + l5];
        float2 vreg[32];
        #pragma unroll
        for (int j = 0; j < 32; ++j)
            vreg[j] = *reinterpret_cast<const float2*>(vbase + (size_t)(s0 + j) * C_);

        #pragma unroll 2
        for (int r = 0; r < 8; ++r) {
            const int t = trow + r;
            float4 q4 = qtb[t];
            float sc = q4.x * k4.x + q4.y * k4.y + q4.z * k4.z + q4.w * k4.w;
            if (s0 + l5 > t) sc = -1e30f;
            float mt = sc;
            #pragma unroll
            for (int off = 16; off >= 1; off >>= 1) mt = fmaxf(mt, __shfl_xor(mt, off));
            float mnew = fmaxf(m[r], mt);
            float corr = __expf(m[r] - mnew);
            float p    = __expf(sc - mnew);
            float ps = p;
            #pragma unroll
            for (int off = 16; off >= 1; off >>= 1) ps += __shfl_xor(ps, off);
            m[r] = mnew;
            lsum[r] = lsum[r] * corr + ps;

            float tx0 = 0.f, tx1 = 0.f, ty0 = 0.f, ty1 = 0.f;
            #pragma unroll
            for (int j = 0; j < 32; j += 2) {
                float p0 = readlane_f(p, j);
                float p1 = readlane_f(p, j + 1);
                tx0 += p0 * vreg[j].x;     ty0 += p0 * vreg[j].y;
                tx1 += p1 * vreg[j + 1].x; ty1 += p1 * vreg[j + 1].y;
            }
            acc[r].x = acc[r].x * corr + tx0 + tx1;
            acc[r].y = acc[r].y * corr + ty0 + ty1;
        }
    }

    #pragma unroll
    for (int r = 0; r < 8; ++r) {
        const int t = trow + r;
        float inv = 1.f / lsum[r];
        ushort2 o2;
        o2.x = f2bf(acc[r].x * inv);
        o2.y = f2bf(acc[r].y * inv);
        *reinterpret_cast<ushort2*>(out + (size_t)(b * T_ + t) * C_ + h * HD_ + 2 * lane) = o2;
    }
}

extern "C" void kernel_launch(void* const* d_in, const int* in_sizes, int n_in,
                              void* d_out, int out_size, void* d_ws, size_t ws_size,
                              hipStream_t stream) {
    const float* x     = (const float*)d_in[0];
    const float* Wq    = (const float*)d_in[1];
    const float* Wk    = (const float*)d_in[2];
    const float* Wv    = (const float*)d_in[3];
    const float* Wo    = (const float*)d_in[4];
    const float* scale = (const float*)d_in[5];
    float* out = (float*)d_out;

    char* ws = (char*)d_ws;
    unsigned short* xbf    = (unsigned short*)(ws);                       // 8 MiB
    unsigned short* wvbf   = (unsigned short*)(ws + 8388608);             // 2 MiB
    unsigned short* wobf   = (unsigned short*)(ws + 10485760);            // 2 MiB
    float*          qt     = (float*)(ws + 12582912);                     // 512 KiB
    float*          kt     = (float*)(ws + 13107200);                     // 512 KiB
    float*          vbuf   = (float*)(ws + 13631488);                     // 16 MiB
    unsigned short* attnbf = (unsigned short*)(ws + 30408704);            // 8 MiB
    // total 38,797,312 bytes

    k_f32_to_bf16<<<M_ * C_ / 1024, 256, 0, stream>>>(x,  xbf,  M_ * C_ / 4);
    k_f32_to_bf16<<<C_ * C_ / 1024, 256, 0, stream>>>(Wv, wvbf, C_ * C_ / 4);
    k_f32_to_bf16<<<C_ * C_ / 1024, 256, 0, stream>>>(Wo, wobf, C_ * C_ / 4);

    k_proj_qk<<<M_, 256, 0, stream>>>(x, Wq, Wk, scale, qt, kt);

    k_gemm_bf16<<<(M_ / 128) * (C_ / 128), 256, 0, stream>>>(xbf, wvbf, vbuf, M_, C_, C_);

    k_attn<<<64 * B_ * H_, 256, 0, stream>>>(qt, kt, vbuf, attnbf);

    k_gemm_bf16<<<(M_ / 128) * (C_ / 128), 256, 0, stream>>>(attnbf, wobf, out, M_, C_, C_);
}

// Round 2
// 218.130 us; speedup vs baseline: 2.5171x; 2.5171x over previous
//
#include <hip/hip_runtime.h>
#include <hip/hip_bf16.h>

#define B_  2
#define T_  2048
#define C_  1024
#define H_  8
#define HD_ 128
#define M_  (B_*T_)   // 4096

typedef short  bf16x8 __attribute__((ext_vector_type(8)));
typedef float  f32x4  __attribute__((ext_vector_type(4)));
typedef unsigned short u16x8 __attribute__((ext_vector_type(8)));

typedef const __attribute__((address_space(1))) void* gas_ptr;
typedef __attribute__((address_space(3))) void*       las_ptr;

#define L2E_ 1.4426950408889634f

static __device__ __forceinline__ unsigned short f2bf(float f) {
    unsigned int u = __float_as_uint(f);
    u += 0x7fffu + ((u >> 16) & 1u);   // round-to-nearest-even
    return (unsigned short)(u >> 16);
}

static __device__ __forceinline__ float exp2_fast(float x) {
#if __has_builtin(__builtin_amdgcn_exp2f)
    return __builtin_amdgcn_exp2f(x);
#else
    return exp2f(x);
#endif
}

// ---------------- fp32 -> bf16 conversion (vectorized) ----------------
__global__ __launch_bounds__(256) void k_f32_to_bf16(const float* __restrict__ in,
                                                     unsigned short* __restrict__ out,
                                                     int n4) {
    int i = blockIdx.x * 256 + threadIdx.x;
    if (i >= n4) return;
    float4 v = reinterpret_cast<const float4*>(in)[i];
    ushort4 o;
    o.x = f2bf(v.x); o.y = f2bf(v.y); o.z = f2bf(v.z); o.w = f2bf(v.w);
    reinterpret_cast<ushort4*>(out)[i] = o;
}

// ---------------- q/k tiny projection (tall-skinny GEMM, 16 rows/block) -------
// qt = log2e * [q3*scale, q3.dir]; kt = [k3, k3.dir]   layout [b*H+h][T] float4
__global__ __launch_bounds__(256) void k_proj_qk(const float* __restrict__ x,
                                                 const float* __restrict__ Wq,
                                                 const float* __restrict__ Wk,
                                                 const float* __restrict__ scale_p,
                                                 float* __restrict__ qt,
                                                 float* __restrict__ kt) {
    __shared__ __align__(16) float wl[48][260];
    __shared__ __align__(16) float xl[16][260];
    __shared__ float res[16][48];
    const int tid  = threadIdx.x;
    const int row0 = blockIdx.x << 4;
    const int r    = tid >> 4, sub = tid & 15;
    float a0 = 0.f, a1 = 0.f, a2 = 0.f;

    for (int ch = 0; ch < 4; ++ch) {
        const int k0 = ch * 256;
        #pragma unroll
        for (int i = 0; i < 12; ++i) {
            int fi = i * 256 + tid;            // 0..3071
            int wr = fi >> 6, wc = (fi & 63) * 4;
            const float* src = (wr < 24) ? (Wq + (size_t)wr * C_) : (Wk + (size_t)(wr - 24) * C_);
            *reinterpret_cast<float4*>(&wl[wr][wc]) = *reinterpret_cast<const float4*>(src + k0 + wc);
        }
        #pragma unroll
        for (int i = 0; i < 4; ++i) {
            int fi = i * 256 + tid;            // 0..1023
            int xr = fi >> 6, xc = (fi & 63) * 4;
            *reinterpret_cast<float4*>(&xl[xr][xc]) =
                *reinterpret_cast<const float4*>(x + (size_t)(row0 + xr) * C_ + k0 + xc);
        }
        __syncthreads();
        const int oc = sub * 3;
        #pragma unroll 4
        for (int k = 0; k < 256; k += 4) {
            float4 xv = *reinterpret_cast<const float4*>(&xl[r][k]);
            float4 w0 = *reinterpret_cast<const float4*>(&wl[oc + 0][k]);
            float4 w1 = *reinterpret_cast<const float4*>(&wl[oc + 1][k]);
            float4 w2 = *reinterpret_cast<const float4*>(&wl[oc + 2][k]);
            a0 += xv.x * w0.x + xv.y * w0.y + xv.z * w0.z + xv.w * w0.w;
            a1 += xv.x * w1.x + xv.y * w1.y + xv.z * w1.z + xv.w * w1.w;
            a2 += xv.x * w2.x + xv.y * w2.y + xv.z * w2.z + xv.w * w2.w;
        }
        __syncthreads();
    }
    res[r][sub * 3 + 0] = a0;
    res[r][sub * 3 + 1] = a1;
    res[r][sub * 3 + 2] = a2;
    __syncthreads();

    {   // 16 rows x 16 (isK,h) = 256 threads
        const int rr = tid >> 4, s2 = tid & 15;
        const int isK = s2 >> 3, h = s2 & 7;
        const float r3 = 0.57735026918962576f;
        float d0 = (h & 4) ? r3 : -r3;
        float d1 = (h & 2) ? r3 : -r3;
        float d2 = (h & 1) ? r3 : -r3;
        const float* v3 = &res[rr][isK * 24 + h * 3];
        float a = v3[0], b = v3[1], c = v3[2];
        float ond = a * d0 + b * d1 + c * d2;
        float sc = scale_p[0];
        float4 ov = isK ? make_float4(a, b, c, ond)
                        : make_float4(a * sc * L2E_, b * sc * L2E_, c * sc * L2E_, ond * L2E_);
        float* dst = isK ? kt : qt;
        int grow = row0 + rr;
        int b_ = grow >> 11, t_idx = grow & (T_ - 1);
        reinterpret_cast<float4*>(dst)[(size_t)(b_ * H_ + h) * T_ + t_idx] = ov;
    }
}

// ---------------- bf16 MFMA GEMM: C[M,N] = A[M,K] * B[N,K]^T ----------------
template <int OUT_BF16>
__global__ __launch_bounds__(256) void k_gemm_bf16(const unsigned short* __restrict__ A,
                                                   const unsigned short* __restrict__ Bw,
                                                   void* __restrict__ Cout,
                                                   int Mdim, int Ndim, int Kdim) {
    __shared__ __align__(16) unsigned short lds_a[4][128][8];  // [kq][row][8]
    __shared__ __align__(16) unsigned short lds_b[4][128][8];
    const int tid = threadIdx.x;
    const int nbn = Ndim >> 7;
    const int bm = (blockIdx.x / nbn) << 7;
    const int bn = (blockIdx.x % nbn) << 7;
    const int w = tid >> 6, l = tid & 63;
    const int wm = ((w >> 1) << 6), wn = ((w & 1) << 6);
    const int lh = l & 15, lq = l >> 4;

    f32x4 acc[4][4];
    #pragma unroll
    for (int i = 0; i < 4; ++i)
        #pragma unroll
        for (int j = 0; j < 4; ++j)
            acc[i][j] = (f32x4){0.f, 0.f, 0.f, 0.f};

    for (int k0 = 0; k0 < Kdim; k0 += 32) {
        #pragma unroll
        for (int p = 0; p < 2; ++p) {
            int flat = p * 256 + tid;
            int kq = flat >> 7, row = flat & 127;
            const unsigned short* ga = A + (size_t)(bm + row) * Kdim + k0 + kq * 8;
            __builtin_amdgcn_global_load_lds((gas_ptr)(const void*)ga,
                (las_ptr)(void*)(&lds_a[0][0][0] + (size_t)flat * 8), 16, 0, 0);
            const unsigned short* gb = Bw + (size_t)(bn + row) * Kdim + k0 + kq * 8;
            __builtin_amdgcn_global_load_lds((gas_ptr)(const void*)gb,
                (las_ptr)(void*)(&lds_b[0][0][0] + (size_t)flat * 8), 16, 0, 0);
        }
        __syncthreads();

        bf16x8 af[4], bfr[4];
        #pragma unroll
        for (int f = 0; f < 4; ++f)
            af[f] = *reinterpret_cast<const bf16x8*>(&lds_a[lq][wm + f * 16 + lh][0]);
        #pragma unroll
        for (int f = 0; f < 4; ++f)
            bfr[f] = *reinterpret_cast<const bf16x8*>(&lds_b[lq][wn + f * 16 + lh][0]);
        #pragma unroll
        for (int i = 0; i < 4; ++i)
            #pragma unroll
            for (int j = 0; j < 4; ++j)
                acc[i][j] = __builtin_amdgcn_mfma_f32_16x16x32_bf16(af[i], bfr[j], acc[i][j], 0, 0, 0);
        __syncthreads();
    }

    #pragma unroll
    for (int i = 0; i < 4; ++i) {
        int rbase = bm + wm + i * 16 + lq * 4;
        #pragma unroll
        for (int j = 0; j < 4; ++j) {
            int cidx = bn + wn + j * 16 + lh;
            #pragma unroll
            for (int r = 0; r < 4; ++r) {
                if (OUT_BF16)
                    ((unsigned short*)Cout)[(size_t)(rbase + r) * Ndim + cidx] = f2bf(acc[i][j][r]);
                else
                    ((float*)Cout)[(size_t)(rbase + r) * Ndim + cidx] = acc[i][j][r];
            }
        }
    }
}

// ---------------- V transpose: [b*T+t][h*HD+d] bf16 -> [b*H*HD + h*HD + d][t] ----
__global__ __launch_bounds__(256) void k_transpose_v(const unsigned short* __restrict__ in,
                                                     unsigned short* __restrict__ outp) {
    __shared__ unsigned int t32[64][65];
    const int bidx = blockIdx.x;         // 0..1023
    const int ct = bidx & 15;            // col tile (c dim, 1024/64)
    const int tt = (bidx >> 4) & 31;     // t tile (2048/64)
    const int b  = bidx >> 9;            // batch
    const int c0 = ct << 6, t0 = tt << 6;
    const int tid = threadIdx.x;

    #pragma unroll
    for (int s = 0; s < 2; ++s) {
        int seg = s * 256 + tid;
        int r = seg >> 3, c8 = (seg & 7) * 8;
        u16x8 v = *reinterpret_cast<const u16x8*>(in + (size_t)(b * T_ + t0 + r) * C_ + c0 + c8);
        #pragma unroll
        for (int j = 0; j < 8; ++j) t32[r][c8 + j] = (unsigned int)(unsigned short)v[j];
    }
    __syncthreads();
    #pragma unroll
    for (int s = 0; s < 2; ++s) {
        int seg = s * 256 + tid;
        int c = seg >> 3, t8 = (seg & 7) * 8;
        u16x8 v;
        #pragma unroll
        for (int j = 0; j < 8; ++j) v[j] = (unsigned short)t32[t8 + j][c];
        *reinterpret_cast<u16x8*>(outp + (size_t)(b * C_ + c0 + c) * T_ + t0 + t8) = v;
    }
}

// ---------------- flash attention: fp32 rank-4 scores + MFMA PV ----------------
// grid: 32 qblocks (heavy first) x 16 bh; block: 4 waves, wave w owns 16 q-rows
__global__ __launch_bounds__(256) void k_attn_mfma(const float4* __restrict__ qt,
                                                   const float4* __restrict__ kt,
                                                   const unsigned short* __restrict__ vt,
                                                   unsigned short* __restrict__ out) {
    const int tid = threadIdx.x;
    const int w = tid >> 6, l = tid & 63;
    const int bid = blockIdx.x;
    const int bh  = bid & 15;
    const int qb  = 31 - (bid >> 4);      // heavy q-blocks get low blockIdx
    const int q0  = qb << 6;
    const int lh  = l & 15, lg = l >> 4;
    const int qrow = q0 + w * 16 + lh;    // this lane's P-row (A-frag row)
    const int nt   = ((q0 + w * 16 + 15) >> 5) + 1;

    const float4* qtb = qt + (size_t)bh * T_;
    const float4* ktb = kt + (size_t)bh * T_;
    const unsigned short* vtb = vt + (size_t)bh * HD_ * T_;

    const float4 q4 = qtb[qrow];
    f32x4 acc[8];
    #pragma unroll
    for (int n = 0; n < 8; ++n) acc[n] = (f32x4){0.f, 0.f, 0.f, 0.f};
    float m = -1e30f, lsum = 0.f;

    for (int st = 0; st < nt; ++st) {
        const int s0 = st << 5;
        const int sbase = s0 + lg * 8;    // this lane's 8 s-values (A-frag k)

        float p[8];
        float mt = -1e30f;
        #pragma unroll
        for (int j = 0; j < 8; ++j) {
            float4 k4 = ktb[sbase + j];
            float sc = fmaf(q4.x, k4.x, fmaf(q4.y, k4.y, fmaf(q4.z, k4.z, q4.w * k4.w)));
            sc = (sbase + j > qrow) ? -1e30f : sc;
            p[j] = sc;
            mt = fmaxf(mt, sc);
        }
        mt = fmaxf(mt, __shfl_xor(mt, 16));
        mt = fmaxf(mt, __shfl_xor(mt, 32));
        const float mnew = fmaxf(m, mt);
        const float corr = exp2_fast(m - mnew);
        float ps = 0.f;
        #pragma unroll
        for (int j = 0; j < 8; ++j) { p[j] = exp2_fast(p[j] - mnew); ps += p[j]; }
        ps += __shfl_xor(ps, 16);
        ps += __shfl_xor(ps, 32);
        lsum = lsum * corr + ps;
        m = mnew;

        bf16x8 pa;
        #pragma unroll
        for (int j = 0; j < 8; ++j) pa[j] = (short)f2bf(p[j]);

        // broadcast corr from A-layout (row = l&15) to D-layout (row = lg*4+r)
        float corrD[4];
        #pragma unroll
        for (int r = 0; r < 4; ++r) corrD[r] = __shfl(corr, lg * 20 + r);
        #pragma unroll
        for (int n = 0; n < 8; ++n)
            #pragma unroll
            for (int r = 0; r < 4; ++r) acc[n][r] *= corrD[r];

        #pragma unroll
        for (int n = 0; n < 8; ++n) {
            bf16x8 vf = *reinterpret_cast<const bf16x8*>(vtb + (size_t)(n * 16 + lh) * T_ + sbase);
            acc[n] = __builtin_amdgcn_mfma_f32_16x16x32_bf16(pa, vf, acc[n], 0, 0, 0);
        }
    }

    const float inv = 1.f / lsum;
    float invD[4];
    #pragma unroll
    for (int r = 0; r < 4; ++r) invD[r] = __shfl(inv, lg * 20 + r);

    const int b = bh >> 3, h = bh & 7;
    #pragma unroll
    for (int n = 0; n < 8; ++n) {
        #pragma unroll
        for (int r = 0; r < 4; ++r) {
            int t = q0 + w * 16 + lg * 4 + r;
            int d = n * 16 + lh;
            out[(size_t)(b * T_ + t) * C_ + h * HD_ + d] = f2bf(acc[n][r] * invD[r]);
        }
    }
}

extern "C" void kernel_launch(void* const* d_in, const int* in_sizes, int n_in,
                              void* d_out, int out_size, void* d_ws, size_t ws_size,
                              hipStream_t stream) {
    const float* x     = (const float*)d_in[0];
    const float* Wq    = (const float*)d_in[1];
    const float* Wk    = (const float*)d_in[2];
    const float* Wv    = (const float*)d_in[3];
    const float* Wo    = (const float*)d_in[4];
    const float* scale = (const float*)d_in[5];
    float* out = (float*)d_out;

    char* ws = (char*)d_ws;
    unsigned short* xbf    = (unsigned short*)(ws);                       // 8 MiB
    unsigned short* wvbf   = (unsigned short*)(ws + 8388608);             // 2 MiB
    unsigned short* wobf   = (unsigned short*)(ws + 10485760);            // 2 MiB
    float*          qt     = (float*)(ws + 12582912);                     // 512 KiB
    float*          kt     = (float*)(ws + 13107200);                     // 512 KiB
    unsigned short* vbbf   = (unsigned short*)(ws + 13631488);            // 8 MiB  V bf16 [M][C]
    unsigned short* vt     = (unsigned short*)(ws + 22020096);            // 8 MiB  V^T [bh*HD+d][T]
    unsigned short* attnbf = (unsigned short*)(ws + 30408704);            // 8 MiB
    // total 38,797,312 bytes

    k_f32_to_bf16<<<M_ * C_ / 1024, 256, 0, stream>>>(x,  xbf,  M_ * C_ / 4);
    k_f32_to_bf16<<<C_ * C_ / 1024, 256, 0, stream>>>(Wv, wvbf, C_ * C_ / 4);
    k_f32_to_bf16<<<C_ * C_ / 1024, 256, 0, stream>>>(Wo, wobf, C_ * C_ / 4);

    k_proj_qk<<<M_ / 16, 256, 0, stream>>>(x, Wq, Wk, scale, qt, kt);

    k_gemm_bf16<1><<<(M_ / 128) * (C_ / 128), 256, 0, stream>>>(xbf, wvbf, (void*)vbbf, M_, C_, C_);

    k_transpose_v<<<1024, 256, 0, stream>>>(vbbf, vt);

    k_attn_mfma<<<32 * B_ * H_, 256, 0, stream>>>(
        reinterpret_cast<const float4*>(qt), reinterpret_cast<const float4*>(kt), vt, attnbf);

    k_gemm_bf16<0><<<(M_ / 128) * (C_ / 128), 256, 0, stream>>>(attnbf, wobf, (void*)out, M_, C_, C_);
}

// Round 4
// 186.930 us; speedup vs baseline: 2.9372x; 1.1669x over previous
//
#include <hip/hip_runtime.h>
#include <hip/hip_bf16.h>

#define B_  2
#define T_  2048
#define C_  1024
#define H_  8
#define HD_ 128
#define M_  (B_*T_)   // 4096

typedef short  bf16x8 __attribute__((ext_vector_type(8)));
typedef float  f32x4  __attribute__((ext_vector_type(4)));
typedef unsigned short u16x8 __attribute__((ext_vector_type(8)));

typedef const __attribute__((address_space(1))) void* gas_ptr;
typedef __attribute__((address_space(3))) void*       las_ptr;

#define L2E_ 1.4426950408889634f

static __device__ __forceinline__ unsigned short f2bf(float f) {
    unsigned int u = __float_as_uint(f);
    u += 0x7fffu + ((u >> 16) & 1u);   // round-to-nearest-even
    return (unsigned short)(u >> 16);
}
static __device__ __forceinline__ float bf2f(unsigned short u) {
    return __uint_as_float(((unsigned int)u) << 16);
}
static __device__ __forceinline__ float exp2_fast(float x) {
#if __has_builtin(__builtin_amdgcn_exp2f)
    return __builtin_amdgcn_exp2f(x);
#else
    return exp2f(x);
#endif
}

// ---------------- fused fp32 -> bf16 conversion for x, Wv, Wo ----------------
__global__ __launch_bounds__(256) void k_convert_all(const float* __restrict__ x,
                                                     const float* __restrict__ Wv,
                                                     const float* __restrict__ Wo,
                                                     unsigned short* __restrict__ xbf,
                                                     unsigned short* __restrict__ wvbf,
                                                     unsigned short* __restrict__ wobf) {
    int i = blockIdx.x * 256 + threadIdx.x;      // units of float4; total 1572864
    const float* src; unsigned short* dst; int off;
    if (i < 1048576)      { src = x;  dst = xbf;  off = i; }
    else if (i < 1310720) { src = Wv; dst = wvbf; off = i - 1048576; }
    else                  { src = Wo; dst = wobf; off = i - 1310720; }
    float4 v = reinterpret_cast<const float4*>(src)[off];
    ushort4 o;
    o.x = f2bf(v.x); o.y = f2bf(v.y); o.z = f2bf(v.z); o.w = f2bf(v.w);
    reinterpret_cast<ushort4*>(dst)[off] = o;
}

// ---------------- q/k tiny projection (tall-skinny GEMM, 16 rows/block) -------
// qt = log2e * [q3*scale, q3.dir]; kt = [k3, k3.dir]   layout [b*H+h][T] float4
__global__ __launch_bounds__(256) void k_proj_qk(const float* __restrict__ x,
                                                 const float* __restrict__ Wq,
                                                 const float* __restrict__ Wk,
                                                 const float* __restrict__ scale_p,
                                                 float* __restrict__ qt,
                                                 float* __restrict__ kt) {
    __shared__ __align__(16) float wl[48][260];
    __shared__ __align__(16) float xl[16][260];
    __shared__ float res[16][48];
    const int tid  = threadIdx.x;
    const int row0 = blockIdx.x << 4;
    const int r    = tid >> 4, sub = tid & 15;
    float a0 = 0.f, a1 = 0.f, a2 = 0.f;

    for (int ch = 0; ch < 4; ++ch) {
        const int k0 = ch * 256;
        #pragma unroll
        for (int i = 0; i < 12; ++i) {
            int fi = i * 256 + tid;            // 0..3071
            int wr = fi >> 6, wc = (fi & 63) * 4;
            const float* src = (wr < 24) ? (Wq + (size_t)wr * C_) : (Wk + (size_t)(wr - 24) * C_);
            *reinterpret_cast<float4*>(&wl[wr][wc]) = *reinterpret_cast<const float4*>(src + k0 + wc);
        }
        #pragma unroll
        for (int i = 0; i < 4; ++i) {
            int fi = i * 256 + tid;            // 0..1023
            int xr = fi >> 6, xc = (fi & 63) * 4;
            *reinterpret_cast<float4*>(&xl[xr][xc]) =
                *reinterpret_cast<const float4*>(x + (size_t)(row0 + xr) * C_ + k0 + xc);
        }
        __syncthreads();
        const int oc = sub * 3;
        #pragma unroll 4
        for (int k = 0; k < 256; k += 4) {
            float4 xv = *reinterpret_cast<const float4*>(&xl[r][k]);
            float4 w0 = *reinterpret_cast<const float4*>(&wl[oc + 0][k]);
            float4 w1 = *reinterpret_cast<const float4*>(&wl[oc + 1][k]);
            float4 w2 = *reinterpret_cast<const float4*>(&wl[oc + 2][k]);
            a0 += xv.x * w0.x + xv.y * w0.y + xv.z * w0.z + xv.w * w0.w;
            a1 += xv.x * w1.x + xv.y * w1.y + xv.z * w1.z + xv.w * w1.w;
            a2 += xv.x * w2.x + xv.y * w2.y + xv.z * w2.z + xv.w * w2.w;
        }
        __syncthreads();
    }
    res[r][sub * 3 + 0] = a0;
    res[r][sub * 3 + 1] = a1;
    res[r][sub * 3 + 2] = a2;
    __syncthreads();

    {   // 16 rows x 16 (isK,h) = 256 threads
        const int rr = tid >> 4, s2 = tid & 15;
        const int isK = s2 >> 3, h = s2 & 7;
        const float r3 = 0.57735026918962576f;
        float d0 = (h & 4) ? r3 : -r3;
        float d1 = (h & 2) ? r3 : -r3;
        float d2 = (h & 1) ? r3 : -r3;
        const float* v3 = &res[rr][isK * 24 + h * 3];
        float a = v3[0], b = v3[1], c = v3[2];
        float ond = a * d0 + b * d1 + c * d2;
        float sc = scale_p[0];
        float4 ov = isK ? make_float4(a, b, c, ond)
                        : make_float4(a * sc * L2E_, b * sc * L2E_, c * sc * L2E_, ond * L2E_);
        float* dst = isK ? kt : qt;
        int grow = row0 + rr;
        int b_ = grow >> 11, t_idx = grow & (T_ - 1);
        reinterpret_cast<float4*>(dst)[(size_t)(b_ * H_ + h) * T_ + t_idx] = ov;
    }
}

// ---------------- bf16 MFMA GEMM, 128x64 tile: C = A[M,K] * B[N,K]^T ----------
// MODE 0: fp32 out [M][N].  MODE 2: bf16 out transposed into vt[(b*C+col)][t].
template <int MODE>
__global__ __launch_bounds__(256) void k_gemm128x64(const unsigned short* __restrict__ A,
                                                    const unsigned short* __restrict__ Bw,
                                                    void* __restrict__ Cout,
                                                    int Mdim, int Ndim, int Kdim) {
    __shared__ __align__(16) unsigned short lds_a[4][128][8];  // [kq][row][8]
    __shared__ __align__(16) unsigned short lds_b[4][64][8];
    const int tid = threadIdx.x;
    const int nbn = Ndim >> 6;
    const int bm = (blockIdx.x / nbn) << 7;
    const int bn = (blockIdx.x % nbn) << 6;
    const int w = tid >> 6, l = tid & 63;
    const int wm = (w >> 1) << 6, wn = (w & 1) << 5;
    const int lh = l & 15, lq = l >> 4;

    f32x4 acc[4][2];
    #pragma unroll
    for (int i = 0; i < 4; ++i)
        #pragma unroll
        for (int j = 0; j < 2; ++j)
            acc[i][j] = (f32x4){0.f, 0.f, 0.f, 0.f};

    for (int k0 = 0; k0 < Kdim; k0 += 32) {
        #pragma unroll
        for (int p = 0; p < 2; ++p) {
            int flat = p * 256 + tid;
            int kq = flat >> 7, row = flat & 127;
            __builtin_amdgcn_global_load_lds((gas_ptr)(A + (size_t)(bm + row) * Kdim + k0 + kq * 8),
                (las_ptr)(&lds_a[0][0][0] + (size_t)flat * 8), 16, 0, 0);
        }
        {
            int kq = tid >> 6, row = tid & 63;
            __builtin_amdgcn_global_load_lds((gas_ptr)(Bw + (size_t)(bn + row) * Kdim + k0 + kq * 8),
                (las_ptr)(&lds_b[0][0][0] + (size_t)tid * 8), 16, 0, 0);
        }
        __syncthreads();

        bf16x8 af[4], bfr[2];
        #pragma unroll
        for (int f = 0; f < 4; ++f)
            af[f] = *reinterpret_cast<const bf16x8*>(&lds_a[lq][wm + f * 16 + lh][0]);
        #pragma unroll
        for (int f = 0; f < 2; ++f)
            bfr[f] = *reinterpret_cast<const bf16x8*>(&lds_b[lq][wn + f * 16 + lh][0]);
        #pragma unroll
        for (int i = 0; i < 4; ++i)
            #pragma unroll
            for (int j = 0; j < 2; ++j)
                acc[i][j] = __builtin_amdgcn_mfma_f32_16x16x32_bf16(af[i], bfr[j], acc[i][j], 0, 0, 0);
        __syncthreads();
    }

    if constexpr (MODE == 0) {
        float* Cf = (float*)Cout;
        #pragma unroll
        for (int i = 0; i < 4; ++i) {
            int rbase = bm + wm + i * 16 + lq * 4;
            #pragma unroll
            for (int j = 0; j < 2; ++j) {
                int cidx = bn + wn + j * 16 + lh;
                #pragma unroll
                for (int r = 0; r < 4; ++r)
                    Cf[(size_t)(rbase + r) * Ndim + cidx] = acc[i][j][r];
            }
        }
    } else {
        __shared__ unsigned short ldsT[128][72];
        #pragma unroll
        for (int i = 0; i < 4; ++i)
            #pragma unroll
            for (int j = 0; j < 2; ++j)
                #pragma unroll
                for (int r = 0; r < 4; ++r)
                    ldsT[wm + i * 16 + lq * 4 + r][wn + j * 16 + lh] = f2bf(acc[i][j][r]);
        __syncthreads();
        unsigned short* vt_out = (unsigned short*)Cout;
        int c = tid & 63, part = tid >> 6;
        int b = bm >> 11, t0 = bm & (T_ - 1);
        unsigned short* dst = vt_out + ((size_t)b * C_ + bn + c) * T_ + t0 + part * 32;
        #pragma unroll
        for (int jj = 0; jj < 4; ++jj) {
            u16x8 v;
            #pragma unroll
            for (int k = 0; k < 8; ++k) v[k] = ldsT[part * 32 + jj * 8 + k][c];
            *reinterpret_cast<u16x8*>(dst + jj * 8) = v;
        }
    }
}

// ---------------- flash attention, s-split-2, barrier-free, MFMA PV ----------
// grid: 32 qb (heavy first) x 2 sp x 16 bh = 1024 blocks; 4 indep waves x 16 rows.
// Wave w owns rows [q0+w*16, q0+w*16+16); processes s-tiles st = sp, sp+2, ...
__global__ __launch_bounds__(256) void k_attn_s2(
        const float4* __restrict__ qt, const float4* __restrict__ kt,
        const unsigned short* __restrict__ vt,
        unsigned short* __restrict__ mpart,       // [2][16][2048][128] bf16 (unnormalized)
        float2* __restrict__ mlbuf) {             // [2][16][2048] (m, lsum)
    const int tid = threadIdx.x;
    const int w = tid >> 6, l = tid & 63;
    const int lh = l & 15, lg = l >> 4;
    const int bid = blockIdx.x;
    const int qb = 31 - (bid >> 5);               // heavy q-blocks first
    const int sp = (bid >> 4) & 1, bh = bid & 15;
    const int q0 = qb << 6;
    const int qrow = q0 + w * 16 + lh;            // this lane's P-row (A-frag row)
    const int nt = ((q0 + w * 16 + 15) >> 5) + 1; // 32-col tiles this wave needs

    const float4* qtb = qt + (size_t)bh * T_;
    const float4* ktb = kt + (size_t)bh * T_;
    const unsigned short* vtb = vt + (size_t)bh * HD_ * T_;

    const float4 q4 = qtb[qrow];
    f32x4 acc[8];
    #pragma unroll
    for (int n = 0; n < 8; ++n) acc[n] = (f32x4){0.f, 0.f, 0.f, 0.f};
    float m = -1e30f, lsum = 0.f;

    for (int st = sp; st < nt; st += 2) {
        const int s0 = st << 5;
        const int sbase = s0 + lg * 8;            // this lane's 8 s-cols (A-frag k)

        bf16x8 vreg[8];                           // independent; issue early
        #pragma unroll
        for (int n = 0; n < 8; ++n)
            vreg[n] = *reinterpret_cast<const bf16x8*>(vtb + (size_t)(n * 16 + lh) * T_ + sbase);

        float p[8];
        float mt = -1e30f;
        #pragma unroll
        for (int jj = 0; jj < 8; ++jj) {
            float4 k4 = ktb[sbase + jj];
            float sc = fmaf(q4.x, k4.x, fmaf(q4.y, k4.y, fmaf(q4.z, k4.z, q4.w * k4.w)));
            sc = (sbase + jj > qrow) ? -1e30f : sc;
            p[jj] = sc;
            mt = fmaxf(mt, sc);
        }
        mt = fmaxf(mt, __shfl_xor(mt, 16));
        mt = fmaxf(mt, __shfl_xor(mt, 32));
        if (__any(mt > m + 8.f)) {                // deferred rescale (log2 units)
            float mnew = fmaxf(m, mt);
            float corr = exp2_fast(m - mnew);
            m = mnew;
            lsum *= corr;
            float c0 = __shfl(corr, 4 * lg + 0);  // lane 4*lg+r has lh == frag row lg*4+r
            float c1 = __shfl(corr, 4 * lg + 1);
            float c2 = __shfl(corr, 4 * lg + 2);
            float c3 = __shfl(corr, 4 * lg + 3);
            #pragma unroll
            for (int n = 0; n < 8; ++n) {
                acc[n][0] *= c0; acc[n][1] *= c1; acc[n][2] *= c2; acc[n][3] *= c3;
            }
        }
        float ps = 0.f;
        #pragma unroll
        for (int jj = 0; jj < 8; ++jj) {
            float e = exp2_fast(p[jj] - m);
            e = (sbase + jj > qrow) ? 0.f : e;    // unconditional mask-zero (m may be stale/-inf)
            p[jj] = e;
            ps += e;
        }
        ps += __shfl_xor(ps, 16);
        ps += __shfl_xor(ps, 32);
        lsum += ps;

        bf16x8 pa;
        #pragma unroll
        for (int jj = 0; jj < 8; ++jj) pa[jj] = (short)f2bf(p[jj]);

        #pragma unroll
        for (int n = 0; n < 8; ++n)
            acc[n] = __builtin_amdgcn_mfma_f32_16x16x32_bf16(pa, vreg[n], acc[n], 0, 0, 0);
    }

    unsigned short* mp = mpart + (size_t)(sp * 16 + bh) * T_ * HD_;
    #pragma unroll
    for (int n = 0; n < 8; ++n) {
        #pragma unroll
        for (int r = 0; r < 4; ++r) {
            int row = q0 + w * 16 + lg * 4 + r;   // D-frag row = lg*4+r
            mp[(size_t)row * HD_ + n * 16 + lh] = f2bf(acc[n][r]);
        }
    }
    if (lg == 0)
        mlbuf[(size_t)(sp * 16 + bh) * T_ + qrow] = make_float2(m, lsum);
}

// ---------------- combine the two s-split partials -> attnbf (bf16) ----------
__global__ __launch_bounds__(256) void k_combine(const unsigned short* __restrict__ mpart,
                                                 const float2* __restrict__ mlbuf,
                                                 unsigned short* __restrict__ attnbf) {
    int idx = blockIdx.x * 256 + threadIdx.x;   // [16][2048][32 d-quads]
    int bh = idx >> 16;
    int rem = idx & 65535;
    int t = rem >> 5, d0 = (rem & 31) * 4;
    float2 ml0 = mlbuf[(size_t)bh * T_ + t];
    float2 ml1 = mlbuf[(size_t)(16 + bh) * T_ + t];
    float mg = fmaxf(ml0.x, ml1.x);
    float w0 = exp2_fast(ml0.x - mg), w1 = exp2_fast(ml1.x - mg);
    float inv = 1.f / (ml0.y * w0 + ml1.y * w1);
    const unsigned short* p0 = mpart + ((size_t)bh * T_ + t) * HD_ + d0;
    const unsigned short* p1 = mpart + ((size_t)(16 + bh) * T_ + t) * HD_ + d0;
    ushort4 a0 = *reinterpret_cast<const ushort4*>(p0);
    ushort4 a1 = *reinterpret_cast<const ushort4*>(p1);
    int b = bh >> 3, h = bh & 7;
    ushort4 o;
    o.x = f2bf((bf2f(a0.x) * w0 + bf2f(a1.x) * w1) * inv);
    o.y = f2bf((bf2f(a0.y) * w0 + bf2f(a1.y) * w1) * inv);
    o.z = f2bf((bf2f(a0.z) * w0 + bf2f(a1.z) * w1) * inv);
    o.w = f2bf((bf2f(a0.w) * w0 + bf2f(a1.w) * w1) * inv);
    *reinterpret_cast<ushort4*>(attnbf + ((size_t)(b * T_ + t) * C_ + h * HD_ + d0)) = o;
}

extern "C" void kernel_launch(void* const* d_in, const int* in_sizes, int n_in,
                              void* d_out, int out_size, void* d_ws, size_t ws_size,
                              hipStream_t stream) {
    const float* x     = (const float*)d_in[0];
    const float* Wq    = (const float*)d_in[1];
    const float* Wk    = (const float*)d_in[2];
    const float* Wv    = (const float*)d_in[3];
    const float* Wo    = (const float*)d_in[4];
    const float* scale = (const float*)d_in[5];
    float* out = (float*)d_out;

    char* ws = (char*)d_ws;
    // Lifetime-based layout (27.5 MiB total):
    //   [0,16M)   mpart   (attn->combine)     ALIASES: xbf [0,8M), wvbf [8M,10M) (dead after gemmV)
    //   [16M,16.5M)  qt   [16.5M,17M) kt
    //   [17M,25M) vt (gemmV->attn)            ALIAS: attnbf (combine->gemmO; vt dead)
    //   [25M,27M) wobf    [27M,27.5M) mlbuf
    unsigned short* mpart  = (unsigned short*)(ws);
    unsigned short* xbf    = (unsigned short*)(ws);
    unsigned short* wvbf   = (unsigned short*)(ws + 8388608);
    float*          qt     = (float*)(ws + 16777216);
    float*          kt     = (float*)(ws + 17301504);
    unsigned short* vt     = (unsigned short*)(ws + 17825792);
    unsigned short* attnbf = (unsigned short*)(ws + 17825792);
    unsigned short* wobf   = (unsigned short*)(ws + 26214400);
    float2*         mlbuf  = (float2*)(ws + 28311552);

    k_convert_all<<<6144, 256, 0, stream>>>(x, Wv, Wo, xbf, wvbf, wobf);

    k_proj_qk<<<M_ / 16, 256, 0, stream>>>(x, Wq, Wk, scale, qt, kt);

    k_gemm128x64<2><<<(M_ / 128) * (C_ / 64), 256, 0, stream>>>(xbf, wvbf, (void*)vt, M_, C_, C_);

    k_attn_s2<<<1024, 256, 0, stream>>>(
        reinterpret_cast<const float4*>(qt), reinterpret_cast<const float4*>(kt), vt, mpart, mlbuf);

    k_combine<<<4096, 256, 0, stream>>>(mpart, mlbuf, attnbf);

    k_gemm128x64<0><<<(M_ / 128) * (C_ / 64), 256, 0, stream>>>(attnbf, wobf, (void*)out, M_, C_, C_);
}